// Round 1
// baseline (14.137 us; speedup 1.0000x reference)
//
#include <hip/hip_runtime.h>

#define BLOCK 256

// R = Rz(az) * Rx(ax) * Ry(ay)  (pytorch3d ZXY convention), columns scaled by
// half-sizes; corner[k] = center + s0*u + s1*v + s2*w with CORNER_SIGNS bits.
__device__ __forceinline__ void make_corners(const float* __restrict__ b, float c[24]) {
    const float px = b[0], py = b[1], pz = b[2];
    const float hx = 0.5f * b[3], hy = 0.5f * b[4], hz = 0.5f * b[5];
    const float az = b[6], ax = b[7], ay = b[8];
    float sz, cz, sx, cx, sy, cy;
    sincosf(az, &sz, &cz);
    sincosf(ax, &sx, &cx);
    sincosf(ay, &sy, &cy);
    // columns of R:
    // col0 = [cz*cy - sz*sx*sy, sz*cy + cz*sx*sy, -cx*sy]
    // col1 = [-sz*cx,           cz*cx,             sx   ]
    // col2 = [cz*sy + sz*sx*cy, sz*sy - cz*sx*cy,  cx*cy]
    const float u0 = hx * (cz * cy - sz * sx * sy);
    const float u1 = hx * (sz * cy + cz * sx * sy);
    const float u2 = hx * (-cx * sy);
    const float v0 = hy * (-sz * cx);
    const float v1 = hy * (cz * cx);
    const float v2 = hy * (sx);
    const float w0 = hz * (cz * sy + sz * sx * cy);
    const float w1 = hz * (sz * sy - cz * sx * cy);
    const float w2 = hz * (cx * cy);
#pragma unroll
    for (int k = 0; k < 8; ++k) {
        const float s0 = (k & 4) ? -1.f : 1.f;
        const float s1 = (k & 2) ? -1.f : 1.f;
        const float s2 = (k & 1) ? -1.f : 1.f;
        c[k * 3 + 0] = px + s0 * u0 + s1 * v0 + s2 * w0;
        c[k * 3 + 1] = py + s0 * u1 + s1 * v1 + s2 * w1;
        c[k * 3 + 2] = pz + s0 * u2 + s1 * v2 + s2 * w2;
    }
}

__global__ __launch_bounds__(BLOCK) void bbox_cd_partial(
    const float* __restrict__ src, const float* __restrict__ tgt,
    float* __restrict__ partial, int n) {
    __shared__ float s_src[BLOCK * 9];
    __shared__ float s_tgt[BLOCK * 9];

    const int block_base = blockIdx.x * BLOCK;
    const int nb = min(BLOCK, n - block_base);  // boxes handled by this block
    const int total = nb * 9;

    // coalesced staging: contiguous 9*nb floats per array
    for (int i = threadIdx.x; i < total; i += BLOCK) {
        s_src[i] = src[block_base * 9 + i];
        s_tgt[i] = tgt[block_base * 9 + i];
    }
    __syncthreads();

    float lsum = 0.f;
    const int t = threadIdx.x;
    if (t < nb) {
        float sc[24], tc[24];
        make_corners(&s_src[t * 9], sc);
        make_corners(&s_tgt[t * 9], tc);
        float sum = 0.f;
#pragma unroll
        for (int i = 0; i < 8; ++i) {
            const float ax = sc[i * 3 + 0];
            const float ay = sc[i * 3 + 1];
            const float az = sc[i * 3 + 2];
            float best = 3.4e38f;
#pragma unroll
            for (int j = 0; j < 8; ++j) {
                const float dx = ax - tc[j * 3 + 0];
                const float dy = ay - tc[j * 3 + 1];
                const float dz = az - tc[j * 3 + 2];
                const float d = fmaf(dz, dz, fmaf(dy, dy, dx * dx));
                best = fminf(best, d);
            }
            sum += best;
        }
        lsum = sum;
    }

    // wave (64-lane) shuffle reduction, then cross-wave via LDS
#pragma unroll
    for (int off = 32; off > 0; off >>= 1) lsum += __shfl_down(lsum, off, 64);

    __shared__ float wsum[BLOCK / 64];
    const int wave = threadIdx.x >> 6;
    const int lane = threadIdx.x & 63;
    if (lane == 0) wsum[wave] = lsum;
    __syncthreads();
    if (threadIdx.x == 0) {
        float b = 0.f;
#pragma unroll
        for (int w = 0; w < BLOCK / 64; ++w) b += wsum[w];
        partial[blockIdx.x] = b;
    }
}

__global__ __launch_bounds__(BLOCK) void bbox_cd_final(
    const float* __restrict__ partial, int nblocks, float* __restrict__ out,
    float inv_count) {
    float s = 0.f;
    for (int i = threadIdx.x; i < nblocks; i += BLOCK) s += partial[i];
#pragma unroll
    for (int off = 32; off > 0; off >>= 1) s += __shfl_down(s, off, 64);

    __shared__ float wsum[BLOCK / 64];
    const int wave = threadIdx.x >> 6;
    const int lane = threadIdx.x & 63;
    if (lane == 0) wsum[wave] = s;
    __syncthreads();
    if (threadIdx.x == 0) {
        float b = 0.f;
#pragma unroll
        for (int w = 0; w < BLOCK / 64; ++w) b += wsum[w];
        out[0] = b * inv_count;
    }
}

extern "C" void kernel_launch(void* const* d_in, const int* in_sizes, int n_in,
                              void* d_out, int out_size, void* d_ws, size_t ws_size,
                              hipStream_t stream) {
    const float* src = (const float*)d_in[0];
    const float* tgt = (const float*)d_in[1];
    float* out = (float*)d_out;
    const int n = in_sizes[0] / 9;  // 262144
    const int nblocks = (n + BLOCK - 1) / BLOCK;

    float* partial = (float*)d_ws;  // nblocks floats of scratch

    bbox_cd_partial<<<nblocks, BLOCK, 0, stream>>>(src, tgt, partial, n);
    const float inv_count = 1.0f / (float)((long long)n * 8);
    bbox_cd_final<<<1, BLOCK, 0, stream>>>(partial, nblocks, out, inv_count);
}